// Round 1
// baseline (525.301 us; speedup 1.0000x reference)
//
#include <hip/hip_runtime.h>

// PolyConv: out[n, :] = W[:, 0:64] @ x[n] + W[:, 64:128] @ x[l[n]] + W[:, 128:192] @ x[r[n]] + b
// N = 1,000,000 items, D = 64, O = 64, K = 192.
//
// Strategy: bf16 MFMA (16x16x32), fp32 accumulate. One wave per 16-item tile.
// - A fragments gathered directly from global memory into MFMA A-operand
//   layout (m = lane&15, k-chunk = quad*8) — no LDS staging at all.
// - W (48 KB fp32) preloaded ONCE per wave into registers as bf16 B-fragments
//   (6 K-steps x 4 col-tiles = 96 VGPRs); persistent waves loop over tiles so
//   the preload amortizes (per-tile W re-read from L2 would cost ~90us alone).
// - Nontemporal stores for the 256 MB output stream to keep x resident in L3
//   (the random gathers depend on L3 retaining the 256 MB x array).

typedef __bf16 bf16x8 __attribute__((ext_vector_type(8)));
typedef float floatx4 __attribute__((ext_vector_type(4)));

#define D 64
#define O 64
#define K3 192

__global__ __launch_bounds__(256) void polyconv_kernel(
    const float* __restrict__ x,
    const int* __restrict__ lidx,
    const int* __restrict__ ridx,
    const float* __restrict__ W,
    const float* __restrict__ bias,
    float* __restrict__ out,
    int n_tiles, int total_waves)
{
    const int lane = threadIdx.x & 63;
    const int wave_id = blockIdx.x * (blockDim.x >> 6) + (threadIdx.x >> 6);
    const int col  = lane & 15;   // item-row (A) / output-col (B,D) within tile
    const int quad = lane >> 4;   // 0..3 -> k-chunk of 8

    // ---- Preload B fragments: B[k][n] = W[n][k]; lane l holds
    //      W[16*ct + col][ks*32 + quad*8 + j], j = 0..7 (8 consecutive floats).
    bf16x8 bfrag[6][4];
#pragma unroll
    for (int ct = 0; ct < 4; ++ct) {
        const float* wrow = W + (size_t)(ct * 16 + col) * K3 + quad * 8;
#pragma unroll
        for (int ks = 0; ks < 6; ++ks) {
            floatx4 w0 = *(const floatx4*)(wrow + ks * 32);
            floatx4 w1 = *(const floatx4*)(wrow + ks * 32 + 4);
            bf16x8 f;
            f[0] = (__bf16)w0[0]; f[1] = (__bf16)w0[1];
            f[2] = (__bf16)w0[2]; f[3] = (__bf16)w0[3];
            f[4] = (__bf16)w1[0]; f[5] = (__bf16)w1[1];
            f[6] = (__bf16)w1[2]; f[7] = (__bf16)w1[3];
            bfrag[ks][ct] = f;
        }
    }
    float bi[4];
#pragma unroll
    for (int ct = 0; ct < 4; ++ct) bi[ct] = bias[ct * 16 + col];

    for (int t = wave_id; t < n_tiles; t += total_waves) {
        const int base = t * 16;
        const int item = base + col;
        const int li = lidx[item];
        const int ri = ridx[item];
        // A[m][k]: m = col (this lane's item), k = ks*32 + quad*8 + j.
        // k 0-63 -> x[item], 64-127 -> x[li], 128-191 -> x[ri].
        const float* px = x + (size_t)item * D + quad * 8;
        const float* pl = x + (size_t)li   * D + quad * 8;
        const float* pr = x + (size_t)ri   * D + quad * 8;
        floatx4 v[12];
        v[0]  = *(const floatx4*)(px);      v[1]  = *(const floatx4*)(px + 4);
        v[2]  = *(const floatx4*)(px + 32); v[3]  = *(const floatx4*)(px + 36);
        v[4]  = *(const floatx4*)(pl);      v[5]  = *(const floatx4*)(pl + 4);
        v[6]  = *(const floatx4*)(pl + 32); v[7]  = *(const floatx4*)(pl + 36);
        v[8]  = *(const floatx4*)(pr);      v[9]  = *(const floatx4*)(pr + 4);
        v[10] = *(const floatx4*)(pr + 32); v[11] = *(const floatx4*)(pr + 36);

        bf16x8 afrag[6];
#pragma unroll
        for (int ks = 0; ks < 6; ++ks) {
            floatx4 a0 = v[2 * ks], a1 = v[2 * ks + 1];
            bf16x8 f;
            f[0] = (__bf16)a0[0]; f[1] = (__bf16)a0[1];
            f[2] = (__bf16)a0[2]; f[3] = (__bf16)a0[3];
            f[4] = (__bf16)a1[0]; f[5] = (__bf16)a1[1];
            f[6] = (__bf16)a1[2]; f[7] = (__bf16)a1[3];
            afrag[ks] = f;
        }

        floatx4 acc[4];
#pragma unroll
        for (int ct = 0; ct < 4; ++ct) acc[ct] = (floatx4){0.f, 0.f, 0.f, 0.f};
#pragma unroll
        for (int ct = 0; ct < 4; ++ct)
#pragma unroll
            for (int ks = 0; ks < 6; ++ks)
                acc[ct] = __builtin_amdgcn_mfma_f32_16x16x32_bf16(
                    afrag[ks], bfrag[ks][ct], acc[ct], 0, 0, 0);

        // D[m][n]: m = quad*4 + r, n = ct*16 + col. Nontemporal: don't let the
        // 256MB output stream evict x from L3.
        float* orow = out + (size_t)base * O;
#pragma unroll
        for (int ct = 0; ct < 4; ++ct) {
#pragma unroll
            for (int r = 0; r < 4; ++r) {
                int m = quad * 4 + r;
                __builtin_nontemporal_store(acc[ct][r] + bi[ct],
                                            orow + (size_t)m * O + ct * 16 + col);
            }
        }
    }
}

extern "C" void kernel_launch(void* const* d_in, const int* in_sizes, int n_in,
                              void* d_out, int out_size, void* d_ws, size_t ws_size,
                              hipStream_t stream) {
    const float* x  = (const float*)d_in[0];
    const int*   li = (const int*)d_in[1];
    const int*   ri = (const int*)d_in[2];
    const float* W  = (const float*)d_in[3];
    const float* b  = (const float*)d_in[4];
    float* out = (float*)d_out;

    const int n = in_sizes[1];            // N = 1,000,000 (divisible by 16)
    const int n_tiles = n / 16;           // 62500
    const int blocks = 1024;              // 4096 persistent waves (~2-3/SIMD resident)
    const int total_waves = blocks * 4;
    polyconv_kernel<<<blocks, 256, 0, stream>>>(x, li, ri, W, b, out,
                                                n_tiles, total_waves);
}

// Round 2
// 515.917 us; speedup vs baseline: 1.0182x; 1.0182x over previous
//
#include <hip/hip_runtime.h>

// PolyConv: out[n,:] = Wx@x[n] + Wl@x[l[n]] + Wr@x[r[n]] + b   (N=1e6, D=64, O=64)
//
// R1 post-mortem: 236us, 631MB HBM @2.7TB/s, MfmaUtil 4%, VALUBusy 4.5%.
// 37k cycles/iteration == fully serialized idx->gather->compute chain.
// R2: software-pipeline the persistent loop — double-buffered gather regs
// (va/vb ping-pong) + idx prefetched one tile ahead, so tile t+1's 12 gather
// loads are in flight while tile t computes. Costs ~96 extra VGPRs -> 2
// waves/SIMD, which BDP says is plenty once requests stay in flight.

typedef __bf16 bf16x8 __attribute__((ext_vector_type(8)));
typedef float floatx4 __attribute__((ext_vector_type(4)));

#define D 64
#define O 64
#define K3 192

__device__ __forceinline__ void issue_gather(floatx4 (&v)[12], const float* __restrict__ x,
                                             int item, int li, int ri, int quad) {
    const float* px = x + (size_t)item * D + quad * 8;
    const float* pl = x + (size_t)li   * D + quad * 8;
    const float* pr = x + (size_t)ri   * D + quad * 8;
    v[0]  = *(const floatx4*)(px);      v[1]  = *(const floatx4*)(px + 4);
    v[2]  = *(const floatx4*)(px + 32); v[3]  = *(const floatx4*)(px + 36);
    v[4]  = *(const floatx4*)(pl);      v[5]  = *(const floatx4*)(pl + 4);
    v[6]  = *(const floatx4*)(pl + 32); v[7]  = *(const floatx4*)(pl + 36);
    v[8]  = *(const floatx4*)(pr);      v[9]  = *(const floatx4*)(pr + 4);
    v[10] = *(const floatx4*)(pr + 32); v[11] = *(const floatx4*)(pr + 36);
}

__device__ __forceinline__ void compute_store(const floatx4 (&v)[12],
                                              const bf16x8 (&bfrag)[6][4],
                                              const float (&bi)[4],
                                              float* __restrict__ out,
                                              int base, int col, int quad) {
    bf16x8 afrag[6];
#pragma unroll
    for (int ks = 0; ks < 6; ++ks) {
        floatx4 a0 = v[2 * ks], a1 = v[2 * ks + 1];
        bf16x8 f;
        f[0] = (__bf16)a0[0]; f[1] = (__bf16)a0[1];
        f[2] = (__bf16)a0[2]; f[3] = (__bf16)a0[3];
        f[4] = (__bf16)a1[0]; f[5] = (__bf16)a1[1];
        f[6] = (__bf16)a1[2]; f[7] = (__bf16)a1[3];
        afrag[ks] = f;
    }
    floatx4 acc[4];
#pragma unroll
    for (int ct = 0; ct < 4; ++ct)
        acc[ct] = (floatx4){bi[ct], bi[ct], bi[ct], bi[ct]};  // fuse bias into acc init
#pragma unroll
    for (int ct = 0; ct < 4; ++ct)
#pragma unroll
        for (int ks = 0; ks < 6; ++ks)
            acc[ct] = __builtin_amdgcn_mfma_f32_16x16x32_bf16(
                afrag[ks], bfrag[ks][ct], acc[ct], 0, 0, 0);

    float* orow = out + (size_t)base * O;
#pragma unroll
    for (int ct = 0; ct < 4; ++ct)
#pragma unroll
        for (int r = 0; r < 4; ++r) {
            int m = quad * 4 + r;
            __builtin_nontemporal_store(acc[ct][r],
                                        orow + (size_t)m * O + ct * 16 + col);
        }
}

__global__ __launch_bounds__(256, 2) void polyconv_kernel(
    const float* __restrict__ x,
    const int* __restrict__ lidx,
    const int* __restrict__ ridx,
    const float* __restrict__ W,
    const float* __restrict__ bias,
    float* __restrict__ out,
    int n_tiles, int total_waves)
{
    const int lane = threadIdx.x & 63;
    const int wave_id = blockIdx.x * (blockDim.x >> 6) + (threadIdx.x >> 6);
    const int col  = lane & 15;
    const int quad = lane >> 4;

    // B fragments: lane holds W[16*ct+col][ks*32 + quad*8 + j], j=0..7 (96 VGPRs)
    bf16x8 bfrag[6][4];
#pragma unroll
    for (int ct = 0; ct < 4; ++ct) {
        const float* wrow = W + (size_t)(ct * 16 + col) * K3 + quad * 8;
#pragma unroll
        for (int ks = 0; ks < 6; ++ks) {
            floatx4 w0 = *(const floatx4*)(wrow + ks * 32);
            floatx4 w1 = *(const floatx4*)(wrow + ks * 32 + 4);
            bf16x8 f;
            f[0] = (__bf16)w0[0]; f[1] = (__bf16)w0[1];
            f[2] = (__bf16)w0[2]; f[3] = (__bf16)w0[3];
            f[4] = (__bf16)w1[0]; f[5] = (__bf16)w1[1];
            f[6] = (__bf16)w1[2]; f[7] = (__bf16)w1[3];
            bfrag[ks][ct] = f;
        }
    }
    float bi[4];
#pragma unroll
    for (int ct = 0; ct < 4; ++ct) bi[ct] = bias[ct * 16 + col];

    const int stride = total_waves;
    int t = wave_id;
    if (t >= n_tiles) return;           // wave-uniform

    floatx4 va[12], vb[12];
    int li_n = 0, ri_n = 0;

    // Prologue: gathers for tile t into va; prefetch idx for t+stride.
    {
        int item = t * 16 + col;
        int li = lidx[item], ri = ridx[item];
        issue_gather(va, x, item, li, ri, quad);
    }
    int t1 = t + stride;
    if (t1 < n_tiles) { li_n = lidx[t1 * 16 + col]; ri_n = ridx[t1 * 16 + col]; }

    while (true) {
        // ---- phase A: state in va, issue next into vb ----
        if (t1 < n_tiles) {
            issue_gather(vb, x, t1 * 16 + col, li_n, ri_n, quad);
            int t2 = t1 + stride;
            if (t2 < n_tiles) { li_n = lidx[t2 * 16 + col]; ri_n = ridx[t2 * 16 + col]; }
        }
        compute_store(va, bfrag, bi, out, t * 16, col, quad);
        t = t1; t1 += stride;
        if (t >= n_tiles) break;

        // ---- phase B: state in vb, issue next into va ----
        if (t1 < n_tiles) {
            issue_gather(va, x, t1 * 16 + col, li_n, ri_n, quad);
            int t2 = t1 + stride;
            if (t2 < n_tiles) { li_n = lidx[t2 * 16 + col]; ri_n = ridx[t2 * 16 + col]; }
        }
        compute_store(vb, bfrag, bi, out, t * 16, col, quad);
        t = t1; t1 += stride;
        if (t >= n_tiles) break;
    }
}

extern "C" void kernel_launch(void* const* d_in, const int* in_sizes, int n_in,
                              void* d_out, int out_size, void* d_ws, size_t ws_size,
                              hipStream_t stream) {
    const float* x  = (const float*)d_in[0];
    const int*   li = (const int*)d_in[1];
    const int*   ri = (const int*)d_in[2];
    const float* W  = (const float*)d_in[3];
    const float* b  = (const float*)d_in[4];
    float* out = (float*)d_out;

    const int n = in_sizes[1];          // N = 1,000,000
    const int n_tiles = n / 16;         // 62500
    const int blocks = 512;             // 2 blocks/CU at 2 waves/SIMD
    const int total_waves = blocks * 4;
    polyconv_kernel<<<blocks, 256, 0, stream>>>(x, li, ri, W, b, out,
                                                n_tiles, total_waves);
}